// Round 7
// baseline (377.357 us; speedup 1.0000x reference)
//
#include <hip/hip_runtime.h>
#include <math.h>

#define BB 4
#define CC 64
#define OO 64
#define HH 128
#define WWD 128
#define HWP (HH*WWD)   // 16384

typedef short bf16x8 __attribute__((ext_vector_type(8)));
typedef float f32x4  __attribute__((ext_vector_type(4)));

__device__ __forceinline__ unsigned short bf16_rne(float f) {
    unsigned u = __float_as_uint(f);
    u += 0x7fffu + ((u >> 16) & 1u);
    return (unsigned short)(u >> 16);
}
__device__ __forceinline__ float bf16_tof(unsigned short h) {
    return __uint_as_float((unsigned)h << 16);
}

// ---------------------------------------------------------------------------
// Kernel 1: W[o][c][3][3] fp32 -> Whi/Wlo[k][o][c] bf16 hi/lo split.
// grid: 288 x 256
// ---------------------------------------------------------------------------
__global__ __launch_bounds__(256) void wtrans_kernel(
    const float* __restrict__ W1, const float* __restrict__ W2,
    unsigned short* __restrict__ Wh1, unsigned short* __restrict__ Wl1,
    unsigned short* __restrict__ Wh2, unsigned short* __restrict__ Wl2)
{
    int idx = blockIdx.x * 256 + threadIdx.x;
    const int n = OO * CC * 9;           // 36864
    const float* src;
    unsigned short *dh, *dl;
    if (idx >= n) { src = W2; dh = Wh2; dl = Wl2; idx -= n; }
    else          { src = W1; dh = Wh1; dl = Wl1; }
    int c = idx & 63;
    int o = (idx >> 6) & 63;
    int k = idx >> 12;
    float w = src[(o * CC + c) * 9 + k];
    unsigned short hi = bf16_rne(w);
    unsigned short lo = bf16_rne(w - bf16_tof(hi));
    dh[idx] = hi;
    dl[idx] = lo;
}

// ---------------------------------------------------------------------------
// Kernel 1b: NCHW -> NHWC transpose of x (fp32). Block = (b, 64-px row seg).
// LDS tile 64ch x 64px padded to 65 (conflict-free both phases).
// grid: 1024 x 256.
// ---------------------------------------------------------------------------
__global__ __launch_bounds__(256) void nhwc_kernel(
    const float* __restrict__ x, float* __restrict__ xh)
{
    __shared__ float s[64 * 65];
    int t = threadIdx.x;
    int g = blockIdx.x;
    int b = g >> 8;
    int p0 = (g & 255) * 64;
    int p  = t & 63;
    int c4 = t >> 6;
    const float* xb = x + (size_t)b * CC * HWP + p0;
#pragma unroll
    for (int i = 0; i < 16; ++i) {
        int c = c4 * 16 + i;
        s[c * 65 + p] = xb[(size_t)c * HWP + p];
    }
    __syncthreads();
    float* xo = xh + ((size_t)b * HWP + p0) * 64;
    int c = t & 63;
#pragma unroll
    for (int i = 0; i < 16; ++i) {
        int px = c4 * 16 + i;
        xo[px * 64 + c] = s[c * 65 + px];
    }
}

// ---------------------------------------------------------------------------
// Kernel 2: FUSED offsets-conv + arconv. NHWC feature input (xh), vectorized
// dwordx4 gathers, barrier-free 9-tap loop, hi/lo 3-product MFMA numerics,
// XCD-aware block swizzle (slab = 2 batches x 32 rows per XCD -> L2-resident).
// mode 1: out = relu(acc+bias), written NHWC (t1 for layer 2).
// mode 2: out = resid + acc + bias, written NCHW (final output).
// ---------------------------------------------------------------------------
__global__ __launch_bounds__(256) void arconv_kernel(
    const float*          __restrict__ xh,    // [B,H,W,C] fp32
    const unsigned short* __restrict__ Whi,   // [9][O][C] bf16 hi
    const unsigned short* __restrict__ Wlo,   // [9][O][C] bf16 lo
    const float*          __restrict__ woff,  // [2,C,3,3]
    const float*          __restrict__ boff,  // [2]
    const float*          __restrict__ bias,  // [O]
    const int* __restrict__ lo_p, const int* __restrict__ hi_p,
    const float* __restrict__ resid,          // NCHW x (mode 2)
    float* __restrict__ out, int mode)
{
    __shared__ float swo[2 * CC * 9];    // offset-conv weights, 4.5 KB
    __shared__ float red[2][4][64];      // c-quarter partials, 2 KB
    __shared__ float rfs[2][64];         // rf_h/2, rf_w/2 per pixel

    int t = threadIdx.x;

    // ---- XCD-aware swizzle: g&7 = slab (XCD via %8 round-robin dispatch) ----
    int g    = blockIdx.x;
    int s    = g & 7;
    int r    = g >> 3;                       // [0,128): 2 batches x 64 tiles
    int b    = ((s >> 2) << 1) | (r >> 6);   // batch
    int tile = ((s & 3) << 6) | (r & 63);    // tile in [0,256)
    int p0   = tile * 64;
    int y    = p0 >> 7;          // all 64 px share one row
    int xb   = p0 & 127;

    const float* xhb = xh + (size_t)b * HWP * 64;

    // ---------------- phase 0: fused offsets conv (NHWC) ----------------
    for (int i = t; i < 2 * CC * 9; i += 256) swo[i] = woff[i];

    int p   = t & 63;
    int cq  = t >> 6;
    int xx0 = xb + p;
    int c0p = cq * 16;
    __syncthreads();

    {
        float a0 = 0.f, a1 = 0.f;
#pragma unroll
        for (int ky = 0; ky < 3; ++ky) {
            int yy = y + ky - 1;
            bool yok = (unsigned)yy < (unsigned)HH;
#pragma unroll
            for (int kx = 0; kx < 3; ++kx) {
                int xx = xx0 + kx - 1;
                if (yok && (unsigned)xx < (unsigned)WWD) {
                    const float* vp = xhb + (size_t)(yy * WWD + xx) * 64 + c0p;
                    union { float f[16]; float4 q[4]; } v;
                    v.q[0] = ((const float4*)vp)[0];
                    v.q[1] = ((const float4*)vp)[1];
                    v.q[2] = ((const float4*)vp)[2];
                    v.q[3] = ((const float4*)vp)[3];
                    int kk = ky * 3 + kx;
#pragma unroll
                    for (int j = 0; j < 16; ++j) {
                        a0 = fmaf(v.f[j], swo[(c0p + j) * 9 + kk], a0);
                        a1 = fmaf(v.f[j], swo[(CC + c0p + j) * 9 + kk], a1);
                    }
                }
            }
        }
        red[0][cq][p] = a0;
        red[1][cq][p] = a1;
    }
    __syncthreads();
    if (t < 128) {
        int ch = t >> 6;       // 0 = h, 1 = w
        int pp = t & 63;
        float flo = (float)lo_p[0];
        float fhi = (float)hi_p[0];
        float sv = red[ch][0][pp] + red[ch][1][pp] + red[ch][2][pp]
                 + red[ch][3][pp] + boff[ch];
        float gg = 1.f / (1.f + expf(-sv));
        rfs[ch][pp] = (flo + (fhi - flo) * gg) * 0.5f;   // pre-halved
    }
    __syncthreads();

    // ---------------- phase 1: barrier-free sample + MFMA ----------------
    int lane = t & 63;
    int wv   = t >> 6;
    int nidx = lane & 15;
    int quad = lane >> 4;
    int px   = wv * 16 + nidx;       // this thread's pixel in the segment

    float rh = rfs[0][px];
    float rw = rfs[1][px];
    float fy = (float)y;
    float fx = (float)(xb + px);
    int cb0 = quad * 8;          // ks=0 channels
    int cb1 = 32 + quad * 8;     // ks=1 channels

    f32x4 acc[4] = {};

    for (int k = 0; k < 9; ++k) {
        float dy = (float)(k / 3 - 1);
        float dx = (float)(k % 3 - 1);
        float ys = fy + dy * rh;
        float xs = fx + dx * rw;
        float y0f = floorf(ys), x0f = floorf(xs);
        float ty = ys - y0f, tx = xs - x0f;
        int iy0 = min(max((int)y0f, 0), HH - 1);
        int iy1 = min(iy0 + 1, HH - 1);
        int ix0 = min(max((int)x0f, 0), WWD - 1);
        int ix1 = min(ix0 + 1, WWD - 1);
        float w00 = (1.f - ty) * (1.f - tx);
        float w01 = (1.f - ty) * tx;
        float w10 = ty * (1.f - tx);
        float w11 = ty * tx;
        const float* pb00 = xhb + (size_t)(iy0 * WWD + ix0) * 64;
        const float* pb01 = xhb + (size_t)(iy0 * WWD + ix1) * 64;
        const float* pb10 = xhb + (size_t)(iy1 * WWD + ix0) * 64;
        const float* pb11 = xhb + (size_t)(iy1 * WWD + ix1) * 64;

        union { unsigned short h[8]; bf16x8 v; } b0h, b0l, b1h, b1l;
        // half ks=0: 8 contiguous channels, 2 dwordx4 per corner
        {
            union { float f[8]; float4 q[2]; } A, B_, C_, D_;
            A.q[0]  = *(const float4*)(pb00 + cb0); A.q[1]  = *(const float4*)(pb00 + cb0 + 4);
            B_.q[0] = *(const float4*)(pb01 + cb0); B_.q[1] = *(const float4*)(pb01 + cb0 + 4);
            C_.q[0] = *(const float4*)(pb10 + cb0); C_.q[1] = *(const float4*)(pb10 + cb0 + 4);
            D_.q[0] = *(const float4*)(pb11 + cb0); D_.q[1] = *(const float4*)(pb11 + cb0 + 4);
#pragma unroll
            for (int j = 0; j < 8; ++j) {
                float sv = w00 * A.f[j] + w01 * B_.f[j] + w10 * C_.f[j] + w11 * D_.f[j];
                unsigned short hs = bf16_rne(sv);
                b0h.h[j] = hs;
                b0l.h[j] = bf16_rne(sv - bf16_tof(hs));
            }
        }
        // half ks=1
        {
            union { float f[8]; float4 q[2]; } A, B_, C_, D_;
            A.q[0]  = *(const float4*)(pb00 + cb1); A.q[1]  = *(const float4*)(pb00 + cb1 + 4);
            B_.q[0] = *(const float4*)(pb01 + cb1); B_.q[1] = *(const float4*)(pb01 + cb1 + 4);
            C_.q[0] = *(const float4*)(pb10 + cb1); C_.q[1] = *(const float4*)(pb10 + cb1 + 4);
            D_.q[0] = *(const float4*)(pb11 + cb1); D_.q[1] = *(const float4*)(pb11 + cb1 + 4);
#pragma unroll
            for (int j = 0; j < 8; ++j) {
                float sv = w00 * A.f[j] + w01 * B_.f[j] + w10 * C_.f[j] + w11 * D_.f[j];
                unsigned short hs = bf16_rne(sv);
                b1h.h[j] = hs;
                b1l.h[j] = bf16_rne(sv - bf16_tof(hs));
            }
        }

        // A hi/lo fragments from global (L1/L2-hot, verified mapping)
        const unsigned short* whk = Whi + (size_t)k * OO * CC + nidx * CC + quad * 8;
        const unsigned short* wlk = Wlo + (size_t)k * OO * CC + nidx * CC + quad * 8;
#pragma unroll
        for (int mt = 0; mt < 4; ++mt) {
            bf16x8 ah0 = *(const bf16x8*)(whk + mt * 16 * CC);        // ks=0
            bf16x8 al0 = *(const bf16x8*)(wlk + mt * 16 * CC);
            acc[mt] = __builtin_amdgcn_mfma_f32_16x16x32_bf16(ah0, b0h.v, acc[mt], 0, 0, 0);
            acc[mt] = __builtin_amdgcn_mfma_f32_16x16x32_bf16(al0, b0h.v, acc[mt], 0, 0, 0);
            acc[mt] = __builtin_amdgcn_mfma_f32_16x16x32_bf16(ah0, b0l.v, acc[mt], 0, 0, 0);
            bf16x8 ah1 = *(const bf16x8*)(whk + mt * 16 * CC + 32);   // ks=1
            bf16x8 al1 = *(const bf16x8*)(wlk + mt * 16 * CC + 32);
            acc[mt] = __builtin_amdgcn_mfma_f32_16x16x32_bf16(ah1, b1h.v, acc[mt], 0, 0, 0);
            acc[mt] = __builtin_amdgcn_mfma_f32_16x16x32_bf16(al1, b1h.v, acc[mt], 0, 0, 0);
            acc[mt] = __builtin_amdgcn_mfma_f32_16x16x32_bf16(ah1, b1l.v, acc[mt], 0, 0, 0);
        }
    }

    // ---------------- epilogue ----------------
    if (mode == 1) {
        // NHWC store: pixel (p0+px), channels o = mt*16 + quad*4 .. +4
        float* op = out + ((size_t)b * HWP + p0 + px) * 64;
#pragma unroll
        for (int mt = 0; mt < 4; ++mt) {
            int o = mt * 16 + quad * 4;
            float4 rv;
            rv.x = fmaxf(acc[mt][0] + bias[o + 0], 0.f);
            rv.y = fmaxf(acc[mt][1] + bias[o + 1], 0.f);
            rv.z = fmaxf(acc[mt][2] + bias[o + 2], 0.f);
            rv.w = fmaxf(acc[mt][3] + bias[o + 3], 0.f);
            *(float4*)(op + o) = rv;
        }
    } else {
        int pxg = p0 + px;
#pragma unroll
        for (int mt = 0; mt < 4; ++mt) {
#pragma unroll
            for (int rr = 0; rr < 4; ++rr) {
                int o = mt * 16 + quad * 4 + rr;
                float v = acc[mt][rr] + bias[o];
                size_t idx = (size_t)(b * OO + o) * HWP + pxg;
                v += resid[idx];
                out[idx] = v;
            }
        }
    }
}

// ---------------------------------------------------------------------------
extern "C" void kernel_launch(void* const* d_in, const int* in_sizes, int n_in,
                              void* d_out, int out_size, void* d_ws, size_t ws_size,
                              hipStream_t stream) {
    const float* x      = (const float*)d_in[0];
    const float* w_off1 = (const float*)d_in[1];
    const float* b_off1 = (const float*)d_in[2];
    const float* W1     = (const float*)d_in[3];
    const float* b1     = (const float*)d_in[4];
    const float* w_off2 = (const float*)d_in[5];
    const float* b_off2 = (const float*)d_in[6];
    const float* W2     = (const float*)d_in[7];
    const float* b2     = (const float*)d_in[8];
    const int*   lo_p   = (const int*)d_in[10];
    const int*   hi_p   = (const int*)d_in[11];
    float* outp = (float*)d_out;

    float* wsf = (float*)d_ws;
    float* t1  = wsf;                                        // B*HW*C f32 (NHWC)
    unsigned short* Wh1 = (unsigned short*)(t1 + (size_t)BB * CC * HWP);
    unsigned short* Wl1 = Wh1 + OO * CC * 9;                 // 36864 each
    unsigned short* Wh2 = Wl1 + OO * CC * 9;
    unsigned short* Wl2 = Wh2 + OO * CC * 9;

    // xh (NHWC copy of x) lives in d_out: dead before layer 2 writes output.
    float* xh = outp;

    // 1. weight transpose + hi/lo split; x -> NHWC
    wtrans_kernel<<<288, 256, 0, stream>>>(W1, W2, Wh1, Wl1, Wh2, Wl2);
    nhwc_kernel<<<1024, 256, 0, stream>>>(x, xh);

    // 2. layer 1: fused offsets + arconv + relu -> t1 (NHWC)
    arconv_kernel<<<1024, 256, 0, stream>>>(xh, Wh1, Wl1, w_off1, b_off1, b1,
                                            lo_p, hi_p, nullptr, t1, 1);

    // 3. layer 2: fused offsets + arconv + residual -> out (NCHW)
    arconv_kernel<<<1024, 256, 0, stream>>>(t1, Wh2, Wl2, w_off2, b_off2, b2,
                                            lo_p, hi_p, x, outp, 2);
}